// Round 3
// baseline (66.042 us; speedup 1.0000x reference)
//
#include <hip/hip_runtime.h>

// Round 3: R1's exact main loop (simple grid-stride, compiler-pipelined),
// fused finale via per-block atomicAdd to d_out (zeroed by a memset node).
// Isolates R2's regression cause (manual unroll vs fusion).

__global__ __launch_bounds__(256) void mse2_fused(
    const float4* __restrict__ O4, const float4* __restrict__ L4,
    float* __restrict__ out, int n4, float inv_b)
{
    const int tid    = blockIdx.x * blockDim.x + threadIdx.x;
    const int stride = gridDim.x * blockDim.x;
    const int q  = threadIdx.x & 3;      // quad lane: which float4 of the row
    const int c0 = q * 4;                // first column this lane owns

    float acc = 0.0f;

    for (int g = tid; g < n4; g += stride) {
        // g = row*4 + q ; consecutive lanes -> consecutive float4 (coalesced)
        float4 l = L4[g];
        float4 o = O4[g];

        // lab0 lives in lane q==0 of each quad (l.x). Broadcast within quad.
        float lab0 = __shfl(l.x, 0, 4);

        // r = round-half-even(3*lab0); n per reference nesting
        int r = (int)rintf(3.0f * lab0);
        int n; float inv;
        if (lab0 == 0.0f) { n = 1; inv = 1.0f; }
        else if (r == 1)  { n = 3; inv = 0x1.555556p-2f; }   // 1/3
        else if (r == 2)  { n = 6; inv = 0x1.555556p-3f; }   // 1/6
        else if (r == 3)  { n = 9; inv = 0x1.c71c72p-4f; }   // 1/9
        else              { n = 0; inv = 0.0f; }

        float dx = o.x - l.x;
        float dy = o.y - l.y;
        float dz = o.z - l.z;
        float dw = o.w - l.w;

        float s = 0.0f;
        if (c0 + 0 < n) s += dx * dx;
        if (c0 + 1 < n) s += dy * dy;
        if (c0 + 2 < n) s += dz * dz;
        if (c0 + 3 < n) s += dw * dw;

        // quad reduction: lane q==0 ends with the row's masked sum
        s += __shfl_xor(s, 1, 4);
        s += __shfl_xor(s, 2, 4);

        if (q == 0) acc += s * inv;
    }

    // wave64 reduction
    #pragma unroll
    for (int off = 32; off >= 1; off >>= 1)
        acc += __shfl_down(acc, off, 64);

    __shared__ float red[4];
    const int wave = threadIdx.x >> 6;
    if ((threadIdx.x & 63) == 0) red[wave] = acc;
    __syncthreads();

    if (threadIdx.x == 0)
        atomicAdd(out, (red[0] + red[1] + red[2] + red[3]) * inv_b);
}

extern "C" void kernel_launch(void* const* d_in, const int* in_sizes, int n_in,
                              void* d_out, int out_size, void* d_ws, size_t ws_size,
                              hipStream_t stream) {
    const float* outputs = (const float*)d_in[0];
    const float* labels  = (const float*)d_in[1];

    const int total = in_sizes[0];   // B * 16
    const int n4    = total / 4;     // number of float4 elements
    const int b     = total / 16;    // number of rows

    // d_out accumulates via atomics -> zero it every call (graph memset node)
    hipMemsetAsync(d_out, 0, sizeof(float) * out_size, stream);

    mse2_fused<<<2048, 256, 0, stream>>>(
        (const float4*)outputs, (const float4*)labels,
        (float*)d_out, n4, 1.0f / (float)b);
    (void)d_ws; (void)ws_size; (void)n_in;
}

// Round 4
// 46.352 us; speedup vs baseline: 1.4248x; 1.4248x over previous
//
#include <hip/hip_runtime.h>

// Round 4: two-kernel structure (R1's finale — fusion via memset node proved a
// 17us SDMA regression in R3). Kernel1 switched to lane-per-row: 3+3 dwordx4
// loads of each row's first 48B, no shuffles, unroll x2 with unconditional
// bodies. 268 MB mandatory traffic; ~134 MB L3-resident across replays.

__device__ __forceinline__ float row_term(const float4* __restrict__ O4,
                                          const float4* __restrict__ L4,
                                          int r) {
    const int b4 = r * 4;                       // first float4 of row r
    float4 l0 = L4[b4 + 0];
    float4 l1 = L4[b4 + 1];
    float4 l2 = L4[b4 + 2];
    float4 o0 = O4[b4 + 0];
    float4 o1 = O4[b4 + 1];
    float4 o2 = O4[b4 + 2];

    const float lab0 = l0.x;
    const int rr = (int)rintf(3.0f * lab0);     // round-half-even = jnp.round
    int n; float inv;
    if (lab0 == 0.0f) { n = 1; inv = 1.0f; }
    else if (rr == 1) { n = 3; inv = 0x1.555556p-2f; }   // 1/3
    else if (rr == 2) { n = 6; inv = 0x1.555556p-3f; }   // 1/6
    else if (rr == 3) { n = 9; inv = 0x1.c71c72p-4f; }   // 1/9
    else              { n = 0; inv = 0.0f; }

    float d, s = 0.0f;
    d = o0.x - l0.x; s += (0 < n) ? d * d : 0.0f;
    d = o0.y - l0.y; s += (1 < n) ? d * d : 0.0f;
    d = o0.z - l0.z; s += (2 < n) ? d * d : 0.0f;
    d = o0.w - l0.w; s += (3 < n) ? d * d : 0.0f;
    d = o1.x - l1.x; s += (4 < n) ? d * d : 0.0f;
    d = o1.y - l1.y; s += (5 < n) ? d * d : 0.0f;
    d = o1.z - l1.z; s += (6 < n) ? d * d : 0.0f;
    d = o1.w - l1.w; s += (7 < n) ? d * d : 0.0f;
    d = o2.x - l2.x; s += (8 < n) ? d * d : 0.0f;

    return s * inv;
}

__global__ __launch_bounds__(256) void mse2_rows(
    const float4* __restrict__ O4, const float4* __restrict__ L4,
    float* __restrict__ partial, int nrows)
{
    const int tid    = blockIdx.x * blockDim.x + threadIdx.x;
    const int stride = gridDim.x * blockDim.x;

    float acc = 0.0f;

    int r = tid;
    // unroll x2, unconditional bodies (12 independent loads in flight)
    for (; r + stride < nrows; r += 2 * stride) {
        acc += row_term(O4, L4, r);
        acc += row_term(O4, L4, r + stride);
    }
    for (; r < nrows; r += stride)
        acc += row_term(O4, L4, r);

    // wave64 reduction
    #pragma unroll
    for (int off = 32; off >= 1; off >>= 1)
        acc += __shfl_down(acc, off, 64);

    __shared__ float red[4];
    const int wave = threadIdx.x >> 6;
    if ((threadIdx.x & 63) == 0) red[wave] = acc;
    __syncthreads();

    if (threadIdx.x == 0)
        partial[blockIdx.x] = red[0] + red[1] + red[2] + red[3];
}

__global__ __launch_bounds__(256) void mse2_final(
    const float* __restrict__ partial, int nb,
    float* __restrict__ out, float inv_b)
{
    float acc = 0.0f;
    for (int i = threadIdx.x; i < nb; i += blockDim.x)
        acc += partial[i];

    #pragma unroll
    for (int off = 32; off >= 1; off >>= 1)
        acc += __shfl_down(acc, off, 64);

    __shared__ float red[4];
    const int wave = threadIdx.x >> 6;
    if ((threadIdx.x & 63) == 0) red[wave] = acc;
    __syncthreads();

    if (threadIdx.x == 0)
        out[0] = (red[0] + red[1] + red[2] + red[3]) * inv_b;
}

extern "C" void kernel_launch(void* const* d_in, const int* in_sizes, int n_in,
                              void* d_out, int out_size, void* d_ws, size_t ws_size,
                              hipStream_t stream) {
    const float* outputs = (const float*)d_in[0];
    const float* labels  = (const float*)d_in[1];

    const int total = in_sizes[0];   // B * 16
    const int nrows = total / 16;    // B
    const int b     = nrows;

    int threads = 256;
    int blocks  = 2048;
    int max_blocks = (int)(ws_size / sizeof(float));
    if (max_blocks < 1) max_blocks = 1;
    if (blocks > max_blocks) blocks = max_blocks;

    float* partial = (float*)d_ws;

    mse2_rows<<<blocks, threads, 0, stream>>>(
        (const float4*)outputs, (const float4*)labels, partial, nrows);
    mse2_final<<<1, 256, 0, stream>>>(
        partial, blocks, (float*)d_out, 1.0f / (float)b);
    (void)n_in; (void)d_out; (void)out_size;
}